// Round 6
// baseline (111.324 us; speedup 1.0000x reference)
//
#include <hip/hip_runtime.h>
#include <hip/hip_bf16.h>

#define NB 8
#define SS 4096
#define DD 1024
#define NI 4094
#define NT 32       // K-tiles (BK=32)
#define BK 32

typedef __attribute__((ext_vector_type(8))) short short8;
typedef __attribute__((ext_vector_type(4))) float f32x4;

// ---- ws layout (bytes) ----
#define WB_OFF 0                           // Wb bf16 [1024][1024] swizzled   (2 MB)
#define XB_OFF (2*1024*1024)               // xb bf16 [8][4096][1024] swizzled(64 MB)
#define YB_OFF (XB_OFF + NB*SS*DD*2)       // ybnd bf16 [8][16][4][1024]      (1 MB)
#define PN_OFF (YB_OFF + NB*16*4*1024*2)   // pn f32 [8][4096][4]
#define PC_OFF (PN_OFF + NB*SS*4*4)        // pc f32 [8][4096][4]

// Swizzle: within each 32-k group (4 x 16B slots), logical slot s of row r is
// stored at physical slot s ^ ((r>>1)&3). Involution; baked into converters so
// gemm's global_load_lds sources stay LINEAR; ds_read applies the same XOR.

__device__ __forceinline__ unsigned short f2bf(float f) {
    union { float f; unsigned int u; } v; v.f = f;
    unsigned int r = v.u + 0x7FFFu + ((v.u >> 16) & 1u);   // RNE
    return (unsigned short)(r >> 16);
}
__device__ __forceinline__ float bf2f(unsigned short u) {
    union { unsigned int u; float f; } v; v.u = ((unsigned int)u) << 16;
    return v.f;
}
__device__ __forceinline__ void gload_lds16(const void* g, void* l) {
    __builtin_amdgcn_global_load_lds(
        (const __attribute__((address_space(1))) void*)g,
        (__attribute__((address_space(3))) void*)l, 16, 0, 0);
}

// ---- pass 0a: W -> bf16, slot-swizzled ----
__global__ void conv_w(const float* __restrict__ W, unsigned short* __restrict__ Wb) {
    int tid = blockIdx.x * 256 + threadIdx.x;
    int row = tid >> 7;
    int sl  = tid & 127;
    int k0  = (sl >> 2) * 32;
    int s   = sl & 3;
    const float* p = W + (size_t)row * DD + k0 + s * 8;
    float4 a0 = *(const float4*)p;
    float4 a1 = *(const float4*)(p + 4);
    ushort4 o0, o1;
    o0.x = f2bf(a0.x); o0.y = f2bf(a0.y); o0.z = f2bf(a0.z); o0.w = f2bf(a0.w);
    o1.x = f2bf(a1.x); o1.y = f2bf(a1.y); o1.z = f2bf(a1.z); o1.w = f2bf(a1.w);
    int sw = s ^ ((row >> 1) & 3);
    unsigned short* q = Wb + (size_t)row * DD + k0 + sw * 8;
    *(ushort4*)q = o0;
    *(ushort4*)(q + 4) = o1;
}

// ---- pass 0b: x -> bf16, slot-swizzled ----
__global__ void conv_xb(const float* __restrict__ x, unsigned short* __restrict__ xb) {
    int tid = blockIdx.x * 256 + threadIdx.x;
    int row = tid >> 7;
    int sl  = tid & 127;
    int k0  = (sl >> 2) * 32;
    int s   = sl & 3;
    const float* p = x + (size_t)row * DD + k0 + s * 8;
    float4 a0 = *(const float4*)p;
    float4 a1 = *(const float4*)(p + 4);
    ushort4 o0, o1;
    o0.x = f2bf(a0.x); o0.y = f2bf(a0.y); o0.z = f2bf(a0.z); o0.w = f2bf(a0.w);
    o1.x = f2bf(a1.x); o1.y = f2bf(a1.y); o1.z = f2bf(a1.z); o1.w = f2bf(a1.w);
    int sw = s ^ ((row >> 1) & 3);
    unsigned short* q = xb + (size_t)row * DD + k0 + sw * 8;
    *(ushort4*)q = o0;
    *(ushort4*)(q + 4) = o1;
}

// ---- pass 1: GEMM C = xb @ Wb^T, 256x256 tile, BK=32, 8 waves,
//      4-buffer LDS, stage-3-ahead, reg-fragment double-buffer:
//      iter kt: stage(kt+3) || ds_read frags(kt+1) || MFMA(kt); one
//      counted vmcnt+lgkmcnt+barrier per K-step. Fused diff epilogue.
__launch_bounds__(512, 2)
__global__ void gemm_nc(const unsigned short* __restrict__ xb,
                        const unsigned short* __restrict__ Wb,
                        float* __restrict__ pn, float* __restrict__ pc,
                        unsigned short* __restrict__ ybnd) {
    __shared__ __align__(16) char smem[131072];   // 4 x (A 16K + B 16K)

    const int bid = blockIdx.x;
    const int vb  = (bid & 7) * 64 + (bid >> 3);   // XCD-chunk swizzle (512 = 8*64)
    const int mg  = vb >> 2, bn = vb & 3;          // m-group, n-tile
    const int b   = mg >> 4, mt = mg & 15;
    const int m0  = mt * 256;

    const int t = threadIdx.x;
    const int lane = t & 63, w = t >> 6;           // 8 waves
    const int wr = w >> 2, wc = w & 3;             // 2 x 4 wave grid
    const int lrow = lane & 15, lgrp = lane >> 4;
    const int swo = (((lrow >> 1) & 3) ^ lgrp) << 4;  // per-thread constant XOR slot

    const unsigned short* Abase = xb + ((size_t)b * SS + m0) * DD;
    const unsigned short* Bbase = Wb + (size_t)bn * 256 * DD;

    const int sr0 = w * 16 + (lane >> 2);
    const int sc0 = (lane & 3) * 8;

    f32x4 acc[8][4] = {};

    auto stage = [&](int kt) {
        char* buf = smem + (kt & 3) * 32768;
        const int k0 = kt * BK;
        gload_lds16(Abase + (size_t)sr0 * DD + k0 + sc0,         buf + w * 1024);
        gload_lds16(Abase + (size_t)(sr0 + 128) * DD + k0 + sc0, buf + 8192 + w * 1024);
        gload_lds16(Bbase + (size_t)sr0 * DD + k0 + sc0,         buf + 16384 + w * 1024);
        gload_lds16(Bbase + (size_t)(sr0 + 128) * DD + k0 + sc0, buf + 24576 + w * 1024);
    };
    auto readfrags = [&](int kt, short8 (&af)[8], short8 (&bfv)[4]) {
        const char* A = smem + (kt & 3) * 32768;
        const char* B = A + 16384;
        #pragma unroll
        for (int m = 0; m < 8; ++m)
            af[m] = *(const short8*)(A + (wr * 128 + m * 16 + lrow) * 64 + swo);
        #pragma unroll
        for (int n = 0; n < 4; ++n)
            bfv[n] = *(const short8*)(B + (wc * 64 + n * 16 + lrow) * 64 + swo);
    };
    auto mfma32 = [&](const short8 (&af)[8], const short8 (&bfv)[4]) {
        __builtin_amdgcn_s_setprio(1);
        #pragma unroll
        for (int m = 0; m < 8; ++m)
            #pragma unroll
            for (int n = 0; n < 4; ++n)
                acc[m][n] = __builtin_amdgcn_mfma_f32_16x16x32_bf16(
                    af[m], bfv[n], acc[m][n], 0, 0, 0);
        __builtin_amdgcn_s_setprio(0);
    };

    short8 afA[8], bfA[4], afB[8], bfB[4];

    stage(0); stage(1); stage(2);                       // 12 loads
    asm volatile("s_waitcnt vmcnt(4)" ::: "memory");    // 0 and 1 landed
    __builtin_amdgcn_s_barrier();
    readfrags(0, afA, bfA);

    #pragma unroll 1
    for (int k2 = 0; k2 < NT / 2; ++k2) {
        {   // even kt: consume set A, prefetch into set B
            const int kt = k2 * 2;
            if (kt + 3 < NT) stage(kt + 3);
            readfrags(kt + 1, afB, bfB);                // executes under MFMA below
            mfma32(afA, bfA);
            if (kt < NT - 3) asm volatile("s_waitcnt vmcnt(4) lgkmcnt(0)" ::: "memory");
            else             asm volatile("s_waitcnt vmcnt(0) lgkmcnt(0)" ::: "memory");
            __builtin_amdgcn_s_barrier();
        }
        {   // odd kt: consume set B, prefetch into set A
            const int kt = k2 * 2 + 1;
            if (kt + 3 < NT) stage(kt + 3);
            if (kt < NT - 1) readfrags(kt + 1, afA, bfA);
            mfma32(afB, bfB);
            if (kt < NT - 3) asm volatile("s_waitcnt vmcnt(4) lgkmcnt(0)" ::: "memory");
            else             asm volatile("s_waitcnt vmcnt(0) lgkmcnt(0)" ::: "memory");
            __builtin_amdgcn_s_barrier();
        }
    }

    // ---------------- epilogue ----------------
    unsigned short* Y = (unsigned short*)smem;
    const int YP = 264;   // padded cols

    // chunk A: C rows 0..129
    if (wr == 0) {
        #pragma unroll
        for (int m = 0; m < 8; ++m) {
            int rbase = m * 16 + lgrp * 4;
            #pragma unroll
            for (int n = 0; n < 4; ++n) {
                int col = wc * 64 + n * 16 + lrow;
                #pragma unroll
                for (int j = 0; j < 4; ++j)
                    Y[(rbase + j) * YP + col] = f2bf(acc[m][n][j]);
            }
        }
    } else if (lgrp == 0) {   // rows 128,129 from wr=1, m=0, j=0,1
        #pragma unroll
        for (int n = 0; n < 4; ++n) {
            int col = wc * 64 + n * 16 + lrow;
            #pragma unroll
            for (int j = 0; j < 2; ++j)
                Y[(128 + j) * YP + col] = f2bf(acc[0][n][j]);
        }
    }
    __syncthreads();

    // dump C rows 0,1 (slots 0,1)
    if (t < 256) {
        int rr = t >> 7, cc = (t & 127) * 2;
        ushort2 v;
        v.x = Y[rr * YP + cc]; v.y = Y[rr * YP + cc + 1];
        *(ushort2*)(ybnd + ((size_t)((b * 16 + mt) * 4 + rr)) * 1024 + bn * 256 + cc) = v;
    }
    // reduce rows 0..127
    {
        int r = t >> 2, q = t & 3;
        const unsigned short* y0 = Y + r * YP + q * 64;
        float sn = 0.f, sc = 0.f;
        #pragma unroll
        for (int c8 = 0; c8 < 8; ++c8) {
            short8 v0 = *(const short8*)(y0 + c8 * 8);
            short8 v1 = *(const short8*)(y0 + YP + c8 * 8);
            short8 v2 = *(const short8*)(y0 + 2 * YP + c8 * 8);
            #pragma unroll
            for (int j = 0; j < 8; ++j) {
                float f0 = bf2f((unsigned short)v0[j]);
                float f1 = bf2f((unsigned short)v1[j]);
                float f2 = bf2f((unsigned short)v2[j]);
                float d0 = f1 - f0, d1 = f2 - f1;
                sn += d0 * d0; sc += d0 * d1;
            }
        }
        sn += __shfl_xor(sn, 1); sn += __shfl_xor(sn, 2);
        sc += __shfl_xor(sc, 1); sc += __shfl_xor(sc, 2);
        if (q == 0) {
            size_t o = ((size_t)b * SS + m0 + r) * 4 + bn;
            pn[o] = sn; pc[o] = sc;
        }
    }
    __syncthreads();

    // chunk B: C rows 128..255 -> LDS rows 0..127
    if (wr == 1) {
        #pragma unroll
        for (int m = 0; m < 8; ++m) {
            int rbase = m * 16 + lgrp * 4;
            #pragma unroll
            for (int n = 0; n < 4; ++n) {
                int col = wc * 64 + n * 16 + lrow;
                #pragma unroll
                for (int j = 0; j < 4; ++j)
                    Y[(rbase + j) * YP + col] = f2bf(acc[m][n][j]);
            }
        }
    }
    __syncthreads();

    // dump C rows 254,255 (LDS rows 126,127 -> slots 2,3)
    if (t < 256) {
        int rr = t >> 7, cc = (t & 127) * 2;
        ushort2 v;
        v.x = Y[(126 + rr) * YP + cc]; v.y = Y[(126 + rr) * YP + cc + 1];
        *(ushort2*)(ybnd + ((size_t)((b * 16 + mt) * 4 + 2 + rr)) * 1024 + bn * 256 + cc) = v;
    }
    // reduce rows 128..254
    {
        int r2 = t >> 2, q = t & 3;
        float sn = 0.f, sc = 0.f;
        if (r2 <= 126) {
            const unsigned short* y0 = Y + r2 * YP + q * 64;
            int rc = (r2 < 126) ? 2 : 1;
            #pragma unroll
            for (int c8 = 0; c8 < 8; ++c8) {
                short8 v0 = *(const short8*)(y0 + c8 * 8);
                short8 v1 = *(const short8*)(y0 + YP + c8 * 8);
                short8 v2 = *(const short8*)(y0 + rc * YP + c8 * 8);
                #pragma unroll
                for (int j = 0; j < 8; ++j) {
                    float f0 = bf2f((unsigned short)v0[j]);
                    float f1 = bf2f((unsigned short)v1[j]);
                    float f2 = bf2f((unsigned short)v2[j]);
                    float d0 = f1 - f0, d1 = f2 - f1;
                    sn += d0 * d0; sc += d0 * d1;
                }
            }
        }
        sn += __shfl_xor(sn, 1); sn += __shfl_xor(sn, 2);
        sc += __shfl_xor(sc, 1); sc += __shfl_xor(sc, 2);
        if (q == 0 && r2 <= 126) {
            size_t o = ((size_t)b * SS + m0 + 128 + r2) * 4 + bn;
            pn[o] = sn;
            if (r2 <= 125) pc[o] = sc;
        }
    }
}

// ---- pass 2: cross-tile boundary scores from dumped rows ----
__global__ void bnd_k(const unsigned short* __restrict__ ybnd,
                      float* __restrict__ pn, float* __restrict__ pc) {
    int b = blockIdx.x / 15, mt = blockIdx.x % 15;
    const unsigned short* T0 = ybnd + ((size_t)(b * 16 + mt) * 4) * 1024;
    const unsigned short* T1 = T0 + 4 * 1024;
    int l = threadIdx.x;
    float n255 = 0.f, c254 = 0.f, c255 = 0.f;
    #pragma unroll
    for (int k = 0; k < 16; ++k) {
        int c = l * 16 + k;
        float s2 = bf2f(T0[2 * 1024 + c]);   // C row 254
        float s3 = bf2f(T0[3 * 1024 + c]);   // C row 255
        float u0 = bf2f(T1[0 * 1024 + c]);   // C row 256
        float u1 = bf2f(T1[1 * 1024 + c]);   // C row 257
        float d254 = s3 - s2, d255 = u0 - s3, d256 = u1 - u0;
        n255 += d255 * d255; c254 += d254 * d255; c255 += d255 * d256;
    }
    #pragma unroll
    for (int off = 32; off > 0; off >>= 1) {
        n255 += __shfl_down(n255, off);
        c254 += __shfl_down(c254, off);
        c255 += __shfl_down(c255, off);
    }
    if (l == 0) {
        int i255 = mt * 256 + 255;
        float4 vn = {n255, 0.f, 0.f, 0.f};
        float4 va = {c254, 0.f, 0.f, 0.f};
        float4 vb = {c255, 0.f, 0.f, 0.f};
        *(float4*)(pn + ((size_t)b * SS + i255) * 4) = vn;
        *(float4*)(pc + ((size_t)b * SS + i255 - 1) * 4) = va;
        *(float4*)(pc + ((size_t)b * SS + i255) * 4) = vb;
    }
}

// ---- pass 3: combine partials -> scores -> adj ----
__global__ void score_k(const float* __restrict__ pn, const float* __restrict__ pc,
                        const float* __restrict__ gate, float* __restrict__ out) {
    int tid = blockIdx.x * 256 + threadIdx.x;
    if (tid >= NB * NI) return;
    int b = tid / NI;
    int i = tid - b * NI;
    size_t base = ((size_t)b * SS + i) * 4;
    float n0 = 0.f, n1 = 0.f, c0 = 0.f;
    #pragma unroll
    for (int j = 0; j < 4; ++j) {
        n0 += pn[base + j];
        n1 += pn[base + 4 + j];
        c0 += pc[base + j];
    }
    float d1a = sqrtf(fmaxf(n0, 0.f));
    float d1b = sqrtf(fmaxf(n1, 0.f));
    float d2  = sqrtf(fmaxf(n0 + 2.f * c0 + n1, 0.f));
    float s = fmaxf(1.f - (d1a + d1b - d2) / fmaxf(d2, 1e-6f), 0.f);
    float g = gate[0] * 0.5f;
    out[(size_t)b * SS + i + 1] = g * (s * (1.f / (float)NI) - 0.5f) * 0.1f;
    if (i == 0) {
        float e = g * (-0.5f) * 0.1f;
        out[(size_t)b * SS] = e;
        out[(size_t)b * SS + SS - 1] = e;
    }
}

extern "C" void kernel_launch(void* const* d_in, const int* in_sizes, int n_in,
                              void* d_out, int out_size, void* d_ws, size_t ws_size,
                              hipStream_t stream) {
    const float* x    = (const float*)d_in[0];
    const float* W    = (const float*)d_in[1];
    // d_in[2] (bias) cancels in all distances -> unused
    const float* gate = (const float*)d_in[3];
    float* out = (float*)d_out;
    char* ws = (char*)d_ws;

    unsigned short* Wb   = (unsigned short*)(ws + WB_OFF);
    unsigned short* xb   = (unsigned short*)(ws + XB_OFF);
    unsigned short* ybnd = (unsigned short*)(ws + YB_OFF);
    float* pn = (float*)(ws + PN_OFF);
    float* pc = (float*)(ws + PC_OFF);

    conv_w<<<512, 256, 0, stream>>>(W, Wb);
    conv_xb<<<NB * SS * 128 / 256, 256, 0, stream>>>(x, xb);
    gemm_nc<<<512, 512, 0, stream>>>(xb, Wb, pn, pc, ybnd);
    bnd_k<<<NB * 15, 64, 0, stream>>>(ybnd, pn, pc);
    score_k<<<(NB * NI + 255) / 256, 256, 0, stream>>>(pn, pc, gate, out);
}

// Round 7
// 105.188 us; speedup vs baseline: 1.0583x; 1.0583x over previous
//
#include <hip/hip_runtime.h>
#include <hip/hip_bf16.h>

#define NB 8
#define SS 4096
#define DD 1024
#define NI 4094
#define NKT 16      // K-tiles (BK=64)
#define BK 64

typedef __attribute__((ext_vector_type(8))) short short8;
typedef __attribute__((ext_vector_type(4))) float f32x4;

// ---- ws layout (bytes) ----
#define WB_OFF 0                           // Wb bf16 [1024][1024] swizzled   (2 MB)
#define XB_OFF (2*1024*1024)               // xb bf16 [8][4096][1024] swizzled(64 MB)
#define YB_OFF (XB_OFF + NB*SS*DD*2)       // ybnd bf16 [8][16][4][1024]      (1 MB)
#define PN_OFF (YB_OFF + NB*16*4*1024*2)   // pn f32 [8][4096][4]
#define PC_OFF (PN_OFF + NB*SS*4*4)        // pc f32 [8][4096][4]

// Swizzle: within each 64-elem k-group (8 x 16B slots), logical slot s of row
// r is stored at physical slot s ^ (r&7). Involution; baked into converters so
// gemm's global_load_lds stays LINEAR both sides; ds_read applies the XOR.

__device__ __forceinline__ unsigned short f2bf(float f) {
    union { float f; unsigned int u; } v; v.f = f;
    unsigned int r = v.u + 0x7FFFu + ((v.u >> 16) & 1u);   // RNE
    return (unsigned short)(r >> 16);
}
__device__ __forceinline__ float bf2f(unsigned short u) {
    union { unsigned int u; float f; } v; v.u = ((unsigned int)u) << 16;
    return v.f;
}
__device__ __forceinline__ void gload_lds16(const void* g, void* l) {
    __builtin_amdgcn_global_load_lds(
        (const __attribute__((address_space(1))) void*)g,
        (__attribute__((address_space(3))) void*)l, 16, 0, 0);
}

// ---- pass 0: x -> bf16 and W -> bf16, 8-slot swizzled, one launch ----
__global__ void conv_all(const float* __restrict__ x, const float* __restrict__ W,
                         unsigned short* __restrict__ xb, unsigned short* __restrict__ Wb) {
    int bid = blockIdx.x;
    const float* src; unsigned short* dst; int tid;
    if (bid < 16384) { src = x; dst = xb; tid = bid * 256 + threadIdx.x; }
    else             { src = W; dst = Wb; tid = (bid - 16384) * 256 + threadIdx.x; }
    int row = tid >> 7;
    int sl  = tid & 127;
    int k0  = (sl >> 3) * 64;
    int s   = sl & 7;
    const float* p = src + (size_t)row * DD + k0 + s * 8;
    float4 a0 = *(const float4*)p;
    float4 a1 = *(const float4*)(p + 4);
    ushort4 o0, o1;
    o0.x = f2bf(a0.x); o0.y = f2bf(a0.y); o0.z = f2bf(a0.z); o0.w = f2bf(a0.w);
    o1.x = f2bf(a1.x); o1.y = f2bf(a1.y); o1.z = f2bf(a1.z); o1.w = f2bf(a1.w);
    unsigned short* q = dst + (size_t)row * DD + k0 + ((s ^ (row & 7)) << 3);
    *(ushort4*)q = o0;
    *(ushort4*)(q + 4) = o1;
}

// ---- pass 1: GEMM C = xb @ Wb^T, 256x256 tile, BK=64, 8 waves (2Mx4N),
//      2 x 64KB LDS buffers, 4 phases per K-tile (16 MFMA each), raw
//      s_barrier, burst stage at phase 0, vmcnt(0) only at phase 3 end
//      (loads ~3 phases old by then). Fused adjacent-row-diff epilogue.
__launch_bounds__(512, 2)
__global__ void gemm_nc(const unsigned short* __restrict__ xb,
                        const unsigned short* __restrict__ Wb,
                        float* __restrict__ pn, float* __restrict__ pc,
                        unsigned short* __restrict__ ybnd) {
    __shared__ __align__(16) char smem[131072];   // buf0 @0, buf1 @65536; A @0, B @32768

    const int bid = blockIdx.x;
    const int vb  = (bid & 7) * 64 + (bid >> 3);   // XCD-chunk swizzle (512 = 8*64)
    const int mg  = vb >> 2, bn = vb & 3;
    const int b   = mg >> 4, mt = mg & 15;
    const int m0  = mt * 256;

    const int t = threadIdx.x;
    const int lane = t & 63, w = t >> 6;
    const int wr = w >> 2, wc = w & 3;             // 2(M) x 4(N) waves
    const int lrow = lane & 15, lgrp = lane >> 4;

    const unsigned short* Abase = xb + ((size_t)b * SS + m0) * DD;
    const unsigned short* Bbase = Wb + (size_t)bn * 256 * DD;

    // staging: per op 4 loads; load i: row = i*64 + (t>>3), col LINEAR (t&7)*8
    const int st_sub = t >> 3;
    const int st_c  = (t & 7) * 8;

    f32x4 acc[8][4] = {};

    auto stage_all = [&](int kt, char* buf) {
        const int k0 = kt * BK;
        #pragma unroll
        for (int i = 0; i < 4; ++i) {
            int row = i * 64 + st_sub;
            size_t off = (size_t)row * DD + k0 + st_c;
            gload_lds16(Abase + off, buf + (i * 512 + t) * 16);
            gload_lds16(Bbase + off, buf + 32768 + (i * 512 + t) * 16);
        }
    };
    auto rdA = [&](const char* buf, int mh, int kk, short8 (&dst)[4]) {
        #pragma unroll
        for (int q = 0; q < 4; ++q) {
            int r = wr * 128 + mh * 64 + q * 16 + lrow;
            dst[q] = *(const short8*)(buf + r * 128 + ((((kk << 2) + lgrp) ^ (r & 7)) << 4));
        }
    };
    auto rdB = [&](const char* buf, int kk, short8 (&dst)[4]) {
        #pragma unroll
        for (int q = 0; q < 4; ++q) {
            int r = wc * 64 + q * 16 + lrow;
            dst[q] = *(const short8*)(buf + 32768 + r * 128 + ((((kk << 2) + lgrp) ^ (r & 7)) << 4));
        }
    };
    auto mf16 = [&](int mh, const short8 (&a)[4], const short8 (&bv)[4]) {
        __builtin_amdgcn_s_setprio(1);
        #pragma unroll
        for (int q = 0; q < 4; ++q)
            #pragma unroll
            for (int n = 0; n < 4; ++n)
                acc[mh * 4 + q][n] = __builtin_amdgcn_mfma_f32_16x16x32_bf16(
                    a[q], bv[n], acc[mh * 4 + q][n], 0, 0, 0);
        __builtin_amdgcn_s_setprio(0);
    };

    stage_all(0, smem);
    asm volatile("s_waitcnt vmcnt(0)" ::: "memory");
    __builtin_amdgcn_s_barrier();

    short8 a0[4], a1[4], b0[4], b1[4];
    #pragma unroll 1
    for (int kt = 0; kt < NKT; ++kt) {
        char* cur = smem + (kt & 1) * 65536;
        char* nxt = smem + ((kt + 1) & 1) * 65536;
        // phase 0: reads first (alias-order), then burst-stage next K-tile
        rdA(cur, 0, 0, a0); rdB(cur, 0, b0);
        if (kt < NKT - 1) stage_all(kt + 1, nxt);
        __builtin_amdgcn_s_barrier();
        mf16(0, a0, b0);
        __builtin_amdgcn_s_barrier();
        // phase 1
        rdA(cur, 1, 0, a1);
        __builtin_amdgcn_s_barrier();
        mf16(1, a1, b0);
        __builtin_amdgcn_s_barrier();
        // phase 2
        rdA(cur, 0, 1, a0); rdB(cur, 1, b1);
        __builtin_amdgcn_s_barrier();
        mf16(0, a0, b1);
        __builtin_amdgcn_s_barrier();
        // phase 3
        rdA(cur, 1, 1, a1);
        __builtin_amdgcn_s_barrier();
        mf16(1, a1, b1);
        asm volatile("s_waitcnt vmcnt(0)" ::: "memory");  // loads ~3 phases old: free
        __builtin_amdgcn_s_barrier();
    }

    // ---------------- epilogue ----------------
    unsigned short* Y = (unsigned short*)smem;
    const int YP = 264;   // padded cols

    // chunk A: C rows 0..129
    if (wr == 0) {
        #pragma unroll
        for (int m = 0; m < 8; ++m) {
            int rbase = m * 16 + lgrp * 4;
            #pragma unroll
            for (int n = 0; n < 4; ++n) {
                int col = wc * 64 + n * 16 + lrow;
                #pragma unroll
                for (int j = 0; j < 4; ++j)
                    Y[(rbase + j) * YP + col] = f2bf(acc[m][n][j]);
            }
        }
    } else if (lgrp == 0) {   // rows 128,129 from wr=1, m=0, j=0,1
        #pragma unroll
        for (int n = 0; n < 4; ++n) {
            int col = wc * 64 + n * 16 + lrow;
            #pragma unroll
            for (int j = 0; j < 2; ++j)
                Y[(128 + j) * YP + col] = f2bf(acc[0][n][j]);
        }
    }
    __syncthreads();

    // dump C rows 0,1 (slots 0,1)
    if (t < 256) {
        int rr = t >> 7, cc = (t & 127) * 2;
        ushort2 v;
        v.x = Y[rr * YP + cc]; v.y = Y[rr * YP + cc + 1];
        *(ushort2*)(ybnd + ((size_t)((b * 16 + mt) * 4 + rr)) * 1024 + bn * 256 + cc) = v;
    }
    // reduce rows 0..127
    {
        int r = t >> 2, q = t & 3;
        const unsigned short* y0 = Y + r * YP + q * 64;
        float sn = 0.f, sc = 0.f;
        #pragma unroll
        for (int c8 = 0; c8 < 8; ++c8) {
            short8 v0 = *(const short8*)(y0 + c8 * 8);
            short8 v1 = *(const short8*)(y0 + YP + c8 * 8);
            short8 v2 = *(const short8*)(y0 + 2 * YP + c8 * 8);
            #pragma unroll
            for (int j = 0; j < 8; ++j) {
                float f0 = bf2f((unsigned short)v0[j]);
                float f1 = bf2f((unsigned short)v1[j]);
                float f2 = bf2f((unsigned short)v2[j]);
                float d0 = f1 - f0, d1 = f2 - f1;
                sn += d0 * d0; sc += d0 * d1;
            }
        }
        sn += __shfl_xor(sn, 1); sn += __shfl_xor(sn, 2);
        sc += __shfl_xor(sc, 1); sc += __shfl_xor(sc, 2);
        if (q == 0) {
            size_t o = ((size_t)b * SS + m0 + r) * 4 + bn;
            pn[o] = sn; pc[o] = sc;
        }
    }
    __syncthreads();

    // chunk B: C rows 128..255 -> LDS rows 0..127
    if (wr == 1) {
        #pragma unroll
        for (int m = 0; m < 8; ++m) {
            int rbase = m * 16 + lgrp * 4;
            #pragma unroll
            for (int n = 0; n < 4; ++n) {
                int col = wc * 64 + n * 16 + lrow;
                #pragma unroll
                for (int j = 0; j < 4; ++j)
                    Y[(rbase + j) * YP + col] = f2bf(acc[m][n][j]);
            }
        }
    }
    __syncthreads();

    // dump C rows 254,255 (LDS rows 126,127 -> slots 2,3)
    if (t < 256) {
        int rr = t >> 7, cc = (t & 127) * 2;
        ushort2 v;
        v.x = Y[(126 + rr) * YP + cc]; v.y = Y[(126 + rr) * YP + cc + 1];
        *(ushort2*)(ybnd + ((size_t)((b * 16 + mt) * 4 + 2 + rr)) * 1024 + bn * 256 + cc) = v;
    }
    // reduce rows 128..254
    {
        int r2 = t >> 2, q = t & 3;
        float sn = 0.f, sc = 0.f;
        if (r2 <= 126) {
            const unsigned short* y0 = Y + r2 * YP + q * 64;
            int rc = (r2 < 126) ? 2 : 1;
            #pragma unroll
            for (int c8 = 0; c8 < 8; ++c8) {
                short8 v0 = *(const short8*)(y0 + c8 * 8);
                short8 v1 = *(const short8*)(y0 + YP + c8 * 8);
                short8 v2 = *(const short8*)(y0 + rc * YP + c8 * 8);
                #pragma unroll
                for (int j = 0; j < 8; ++j) {
                    float f0 = bf2f((unsigned short)v0[j]);
                    float f1 = bf2f((unsigned short)v1[j]);
                    float f2 = bf2f((unsigned short)v2[j]);
                    float d0 = f1 - f0, d1 = f2 - f1;
                    sn += d0 * d0; sc += d0 * d1;
                }
            }
        }
        sn += __shfl_xor(sn, 1); sn += __shfl_xor(sn, 2);
        sc += __shfl_xor(sc, 1); sc += __shfl_xor(sc, 2);
        if (q == 0 && r2 <= 126) {
            size_t o = ((size_t)b * SS + m0 + 128 + r2) * 4 + bn;
            pn[o] = sn;
            if (r2 <= 125) pc[o] = sc;
        }
    }
}

// ---- pass 2: cross-tile boundary scores from dumped rows ----
__global__ void bnd_k(const unsigned short* __restrict__ ybnd,
                      float* __restrict__ pn, float* __restrict__ pc) {
    int b = blockIdx.x / 15, mt = blockIdx.x % 15;
    const unsigned short* T0 = ybnd + ((size_t)(b * 16 + mt) * 4) * 1024;
    const unsigned short* T1 = T0 + 4 * 1024;
    int l = threadIdx.x;
    float n255 = 0.f, c254 = 0.f, c255 = 0.f;
    #pragma unroll
    for (int k = 0; k < 16; ++k) {
        int c = l * 16 + k;
        float s2 = bf2f(T0[2 * 1024 + c]);
        float s3 = bf2f(T0[3 * 1024 + c]);
        float u0 = bf2f(T1[0 * 1024 + c]);
        float u1 = bf2f(T1[1 * 1024 + c]);
        float d254 = s3 - s2, d255 = u0 - s3, d256 = u1 - u0;
        n255 += d255 * d255; c254 += d254 * d255; c255 += d255 * d256;
    }
    #pragma unroll
    for (int off = 32; off > 0; off >>= 1) {
        n255 += __shfl_down(n255, off);
        c254 += __shfl_down(c254, off);
        c255 += __shfl_down(c255, off);
    }
    if (l == 0) {
        int i255 = mt * 256 + 255;
        float4 vn = {n255, 0.f, 0.f, 0.f};
        float4 va = {c254, 0.f, 0.f, 0.f};
        float4 vb = {c255, 0.f, 0.f, 0.f};
        *(float4*)(pn + ((size_t)b * SS + i255) * 4) = vn;
        *(float4*)(pc + ((size_t)b * SS + i255 - 1) * 4) = va;
        *(float4*)(pc + ((size_t)b * SS + i255) * 4) = vb;
    }
}

// ---- pass 3: combine partials -> scores -> adj ----
__global__ void score_k(const float* __restrict__ pn, const float* __restrict__ pc,
                        const float* __restrict__ gate, float* __restrict__ out) {
    int tid = blockIdx.x * 256 + threadIdx.x;
    if (tid >= NB * NI) return;
    int b = tid / NI;
    int i = tid - b * NI;
    size_t base = ((size_t)b * SS + i) * 4;
    float n0 = 0.f, n1 = 0.f, c0 = 0.f;
    #pragma unroll
    for (int j = 0; j < 4; ++j) {
        n0 += pn[base + j];
        n1 += pn[base + 4 + j];
        c0 += pc[base + j];
    }
    float d1a = sqrtf(fmaxf(n0, 0.f));
    float d1b = sqrtf(fmaxf(n1, 0.f));
    float d2  = sqrtf(fmaxf(n0 + 2.f * c0 + n1, 0.f));
    float s = fmaxf(1.f - (d1a + d1b - d2) / fmaxf(d2, 1e-6f), 0.f);
    float g = gate[0] * 0.5f;
    out[(size_t)b * SS + i + 1] = g * (s * (1.f / (float)NI) - 0.5f) * 0.1f;
    if (i == 0) {
        float e = g * (-0.5f) * 0.1f;
        out[(size_t)b * SS] = e;
        out[(size_t)b * SS + SS - 1] = e;
    }
}

extern "C" void kernel_launch(void* const* d_in, const int* in_sizes, int n_in,
                              void* d_out, int out_size, void* d_ws, size_t ws_size,
                              hipStream_t stream) {
    const float* x    = (const float*)d_in[0];
    const float* W    = (const float*)d_in[1];
    // d_in[2] (bias) cancels in all distances -> unused
    const float* gate = (const float*)d_in[3];
    float* out = (float*)d_out;
    char* ws = (char*)d_ws;

    unsigned short* Wb   = (unsigned short*)(ws + WB_OFF);
    unsigned short* xb   = (unsigned short*)(ws + XB_OFF);
    unsigned short* ybnd = (unsigned short*)(ws + YB_OFF);
    float* pn = (float*)(ws + PN_OFF);
    float* pc = (float*)(ws + PC_OFF);

    conv_all<<<16896, 256, 0, stream>>>(x, W, xb, Wb);
    gemm_nc<<<512, 512, 0, stream>>>(xb, Wb, pn, pc, ybnd);
    bnd_k<<<NB * 15, 64, 0, stream>>>(ybnd, pn, pc);
    score_k<<<(NB * NI + 255) / 256, 256, 0, stream>>>(pn, pc, gate, out);
}